// Round 8
// baseline (175.714 us; speedup 1.0000x reference)
//
#include <hip/hip_runtime.h>
#include <hip/hip_bf16.h>

#define BTC 16
#define NC 1024
#define DC 128
#define HC 8
#define HDC 16

typedef __attribute__((ext_vector_type(8))) short bf16x8;   // 8 bf16 = 4 VGPR
typedef __attribute__((ext_vector_type(4))) float f32x4;    // MFMA C/D frag 16x16
typedef __attribute__((ext_vector_type(16))) float f32x16;  // MFMA C/D frag 32x32
typedef __attribute__((ext_vector_type(4))) short short4v;  // 4 bf16 = 2 VGPR

#if __has_builtin(__builtin_amdgcn_exp2f)
#define EXP2F(x) __builtin_amdgcn_exp2f(x)
#else
#define EXP2F(x) exp2f(x)
#endif

// q scale: 0.25 (1/sqrt(HD)) * log2(e)  -> attention uses exp2 directly
#define QSCALE 0.36067376022224085f

union PK2 { short4v s4; __hip_bfloat162 h2[2]; };
union PK8 { bf16x8 v; short s[8]; __hip_bfloat162 h2[4]; };

static __device__ inline short f2bf(float f) {               // RNE f32->bf16
    unsigned u = __builtin_bit_cast(unsigned, f);
    u += 0x7fffu + ((u >> 16) & 1u);
    return (short)(u >> 16);
}

// raw workgroup barrier: LDS-visibility only (lgkmcnt), keeps global register
// prefetches (vmcnt) in flight across the barrier (unlike __syncthreads).
#define LDS_BARRIER()                                              \
    do {                                                           \
        asm volatile("s_waitcnt lgkmcnt(0)" ::: "memory");         \
        __builtin_amdgcn_s_barrier();                              \
        asm volatile("" ::: "memory");                             \
    } while (0)

// ---------------- prep: fp32 -> bf16 for x and the 4 weight matrices --------
__global__ __launch_bounds__(256)
void prep_kernel(const float* __restrict__ x,
                 const float* __restrict__ Wq, const float* __restrict__ Wk,
                 const float* __restrict__ Wv, const float* __restrict__ Wo,
                 short* __restrict__ xbf, short* __restrict__ Wbf)
{
    int gid  = blockIdx.x * 256 + threadIdx.x;
    int base = gid * 4;
    const float* src;
    short* dst;
    if (base < 2097152) {                      // x: 16*1024*128
        src = x + base; dst = xbf + base;
    } else {
        int idx = base - 2097152;              // 0..65535 over 4 W's
        int w   = idx >> 14;
        int off = idx & 16383;
        src = ((w == 0) ? Wq : (w == 1) ? Wk : (w == 2) ? Wv : Wo) + off;
        dst = Wbf + w * 16384 + off;
    }
    float4 v = *(const float4*)src;
    PK2 pk;
    pk.h2[0] = __float22bfloat162_rn(make_float2(v.x, v.y));
    pk.h2[1] = __float22bfloat162_rn(make_float2(v.z, v.w));
    *(short4v*)dst = pk.s4;
}

// ---------------- MFMA projection, C = X @ W^T + b --------------------------
// block = 256 thr (4 waves), wave = 16 rows x 128 cols, K-loop 4x32.
// y = 0: q (scale QSCALE), 1: k — BOTH stored head-packed [bt][h][n][16] so
// the attention kernel's per-tile K load is one fully-coalesced 1KB wave load.
// y = 2: v stored transposed vt[bt][d][n] via LDS transpose -> 16B stores.
__global__ __launch_bounds__(256)
void proj_qkv(const short* __restrict__ xbf, const short* __restrict__ Wbf,
              const float* __restrict__ bq, const float* __restrict__ bk,
              const float* __restrict__ bv,
              short* __restrict__ qo, short* __restrict__ ko, short* __restrict__ vto)
{
    __shared__ short T[128 * 72];        // 18.4 KB transpose tile (y==2 only)

    const int y = blockIdx.y;
    const short* W = Wbf + y * 16384;
    const float* bias = (y == 0) ? bq : (y == 1) ? bk : bv;
    const float scale = (y == 0) ? QSCALE : 1.0f;

    const int tid  = threadIdx.x;
    const int wave = tid >> 6;
    const int lane = tid & 63;
    const int l15  = lane & 15;
    const int quad = lane >> 4;
    const int rowA = blockIdx.x * 64 + wave * 16;

    f32x4 acc[8];
#pragma unroll
    for (int t = 0; t < 8; ++t) acc[t] = (f32x4){0.f, 0.f, 0.f, 0.f};

#pragma unroll
    for (int kk = 0; kk < DC; kk += 32) {
        bf16x8 Af = *(const bf16x8*)&xbf[(size_t)(rowA + l15) * DC + kk + quad * 8];
#pragma unroll
        for (int t = 0; t < 8; ++t) {
            bf16x8 Bf = *(const bf16x8*)&W[(t * 16 + l15) * DC + kk + quad * 8];
            acc[t] = __builtin_amdgcn_mfma_f32_16x16x32_bf16(Af, Bf, acc[t], 0, 0, 0);
        }
    }

    if (y == 2) {
        // transpose through LDS: T[c][local_row], row stride 72 shorts (144 B,
        // 16-B aligned for b128 reads; bank-minimal b64 writes)
#pragma unroll
        for (int t = 0; t < 8; ++t) {
            int c = t * 16 + l15;
            float b = bias[c];
            PK2 pk;
            pk.h2[0] = __float22bfloat162_rn(make_float2(acc[t][0] + b, acc[t][1] + b));
            pk.h2[1] = __float22bfloat162_rn(make_float2(acc[t][2] + b, acc[t][3] + b));
            *(short4v*)&T[c * 72 + wave * 16 + quad * 4] = pk.s4;
        }
        __syncthreads();                  // y uniform per block: no divergence
        const int bt = blockIdx.x >> 4;
        const int n0 = (blockIdx.x * 64) & 1023;
        const int chunk = tid & 7;        // 8 chunks x 16 B = one 128-B d-row
        const int dr    = tid >> 3;       // 0..31
#pragma unroll
        for (int rep = 0; rep < 4; ++rep) {
            int d = rep * 32 + dr;
            bf16x8 u = *(const bf16x8*)&T[d * 72 + chunk * 8];
            *(bf16x8*)&vto[((size_t)bt * DC + d) * NC + n0 + chunk * 8] = u;
        }
    } else {
        short* dst = (y == 0) ? qo : ko;
#pragma unroll
        for (int t = 0; t < 8; ++t) {
            int c  = t * 16 + l15;
            int hh = c >> 4, dd = c & 15;
            float b = bias[c];
#pragma unroll
            for (int r = 0; r < 4; ++r) {
                int row = rowA + quad * 4 + r;       // = bt*1024 + n
                int btq = row >> 10, n = row & 1023;
                float val = (acc[t][r] + b) * scale;
                dst[(((size_t)btq * HC + hh) * NC + n) * HDC + dd] = f2bf(val);
            }
        }
    }
}

// out-projection: bf16 ctx in, fp32 out
__global__ __launch_bounds__(256)
void proj_out(const short* __restrict__ cbf, const short* __restrict__ Wobf,
              const float* __restrict__ bo, float* __restrict__ out)
{
    const int tid  = threadIdx.x;
    const int wave = tid >> 6;
    const int lane = tid & 63;
    const int l15  = lane & 15;
    const int quad = lane >> 4;
    const int rowA = blockIdx.x * 64 + wave * 16;

    f32x4 acc[8];
#pragma unroll
    for (int t = 0; t < 8; ++t) acc[t] = (f32x4){0.f, 0.f, 0.f, 0.f};

#pragma unroll
    for (int kk = 0; kk < DC; kk += 32) {
        bf16x8 Af = *(const bf16x8*)&cbf[(size_t)(rowA + l15) * DC + kk + quad * 8];
#pragma unroll
        for (int t = 0; t < 8; ++t) {
            bf16x8 Bf = *(const bf16x8*)&Wobf[(t * 16 + l15) * DC + kk + quad * 8];
            acc[t] = __builtin_amdgcn_mfma_f32_16x16x32_bf16(Af, Bf, acc[t], 0, 0, 0);
        }
    }

#pragma unroll
    for (int t = 0; t < 8; ++t) {
        int c = t * 16 + l15;
        float b = bo[c];
#pragma unroll
        for (int r = 0; r < 4; ++r) {
            int row = rowA + quad * 4 + r;
            out[(size_t)row * DC + c] = acc[t][r] + b;
        }
    }
}

// ---------------- MFMA attention: KVBLK=64, conflict-free LDS ---------------
// block = 256 thr = 4 waves = 4 heads; grid (32 qt, 16 bt, 2 hz) = 1024
// blocks -> 4 blocks/CU. Per wave (1 head, 32 q-rows), per 64-key group it:
//   2x [ S^T = K·Q (mfma_32x32x16, k=d=16); P = exp2(S^T)·adj -> bf16 ->
//        wave-private single-buffered Ps ]
//   PV of group it-1: 8x mfma_16x16x32 from P regs read at END of iter it-1
// Round-8 changes (LDS-unit model: 4.75M conflict cy = 7.7 us/CU + ~15 us of
// inherent DS traffic is the dominant pipe; r4 proved pow2+XOR = 0 conflicts):
//   * As stride 64 floats (256 B pow2), Ps stride 64 shorts (128 B pow2),
//     BOTH XOR-swizzled byte ^ ((row&7)<<4) on write AND read (bijective).
//   * P(it) read back into registers at END of iter it (wave-private, DS
//     in-order) — consumed next iter, LDS latency fully off the path.
//   * V register-carried: V(it) loaded in iter it, consumed iter it+1 — no
//     vmcnt stall inside the PV cluster (r7 regression fixed).
// Carried across the barrier in regs: K(it+1), V(it), adj(it+2), P(it) frags.
__global__ __launch_bounds__(256, 4)
void attn_kernel(const short* __restrict__ qh, const short* __restrict__ kh,
                 const short* __restrict__ vt, const float* __restrict__ adj,
                 short* __restrict__ cb)
{
    __shared__ float As[2][32 * 64];     // adj 32x64 tile dbuf, 16 KB, swizzled
    __shared__ short Ps[4][32 * 64];     // wave-private P (64 keys), 16 KB, swz

    const int tid  = threadIdx.x;
    const int wave = tid >> 6;
    const int lane = tid & 63;
    const int l31  = lane & 31;
    const int hi   = lane >> 5;
    const int l15  = lane & 15;
    const int quad = lane >> 4;
    const int bt   = blockIdx.y;
    const int qt0  = blockIdx.x * 32;
    const int h    = blockIdx.z * 4 + wave;

    const size_t xb = (size_t)bt * NC * DC;
    const size_t hb = ((size_t)bt * HC + h) * NC;    // head-packed row base

    // K A-frag: A[m=key=l31][k=d=hi*8+j]; per-subtile load = kp[key0*HDC]
    const short* kp = kh + (hb + l31) * HDC + hi * 8;
    // V B-frag: B[k=key=quad*8+j][n=d=l15]; per-subtile load = vp[key0+quad*8]
    const short* vp = vt + ((size_t)bt * DC + h * HDC + l15) * NC;
    // Q B-frag: B[k=d=hi*8+j][n=q=l31] (QSCALE folded at proj)
    const bf16x8 Bq = *(const bf16x8*)&qh[(hb + qt0 + l31) * HDC + hi * 8];

    // adj staging: 256 thr x 2 float4 cover the 32x64 f32 tile, coalesced
    const int arow = tid >> 3;            // 0..31
    const float* aptr = adj + (size_t)bt * NC * NC + (size_t)(qt0 + arow) * NC
                        + (tid & 7) * 8;
    const unsigned awz = (unsigned)((arow & 7) << 4);          // stage swizzle
    const unsigned wo  = (unsigned)(arow * 256 + (tid & 7) * 32);
    const unsigned swz = (unsigned)((l31 & 7) << 4);           // exp-side swz
    const unsigned pswz = (unsigned)((l15 & 7) << 4);          // PV-read swz
                                                               // ((16+l15)&7)==(l15&7)

    PK8 ones;
#pragma unroll
    for (int j = 0; j < 8; ++j) ones.s[j] = (short)0x3F80;   // bf16 1.0

    f32x16 Z16;
#pragma unroll
    for (int i = 0; i < 16; ++i) Z16[i] = 0.f;               // hoisted zero C

    f32x4 Cc[2], Cw[2];
#pragma unroll
    for (int s = 0; s < 2; ++s) {
        Cc[s] = (f32x4){0.f, 0.f, 0.f, 0.f};
        Cw[s] = (f32x4){0.f, 0.f, 0.f, 0.f};
    }

    char* Pw = (char*)&Ps[wave][0];      // wave-private P, single-buffered

    // P = exp2(S^T)*adj -> bf16 -> Pw, swizzled pow2 layout (key half H2=0/32).
    // S reg r: key = H2 + (r&3) + 8*(r>>2) + 4*hi.
    // adj read: row l31, float col H2+4hi+8t -> byte (l31*256+(H2+4hi+8t)*4)^swz
    // P write:  row l31, key col  H2+4hi+8t -> byte (l31*128+(H2+4hi+8t)*2)^swz
#define EXPTILE(S, ASB, H2)                                                   \
    do {                                                                      \
        const char* asb = (const char*)(ASB);                                 \
        const unsigned ro = (unsigned)(l31 * 256 + (H2) * 4 + hi * 16);       \
        float4 a0 = *(const float4*)(asb + ((ro +  0) ^ swz));                \
        float4 a1 = *(const float4*)(asb + ((ro + 32) ^ swz));                \
        float4 a2 = *(const float4*)(asb + ((ro + 64) ^ swz));                \
        float4 a3 = *(const float4*)(asb + ((ro + 96) ^ swz));                \
        const unsigned po = (unsigned)(l31 * 128 + (H2) * 2 + hi * 8);        \
        PK2 pk;                                                               \
        pk.h2[0] = __float22bfloat162_rn(                                     \
            make_float2(EXP2F(S[0]) * a0.x, EXP2F(S[1]) * a0.y));             \
        pk.h2[1] = __float22bfloat162_rn(                                     \
            make_float2(EXP2F(S[2]) * a0.z, EXP2F(S[3]) * a0.w));             \
        *(short4v*)(Pw + ((po +  0) ^ swz)) = pk.s4;                          \
        pk.h2[0] = __float22bfloat162_rn(                                     \
            make_float2(EXP2F(S[4]) * a1.x, EXP2F(S[5]) * a1.y));             \
        pk.h2[1] = __float22bfloat162_rn(                                     \
            make_float2(EXP2F(S[6]) * a1.z, EXP2F(S[7]) * a1.w));             \
        *(short4v*)(Pw + ((po + 16) ^ swz)) = pk.s4;                          \
        pk.h2[0] = __float22bfloat162_rn(                                     \
            make_float2(EXP2F(S[8]) * a2.x, EXP2F(S[9]) * a2.y));             \
        pk.h2[1] = __float22bfloat162_rn(                                     \
            make_float2(EXP2F(S[10]) * a2.z, EXP2F(S[11]) * a2.w));           \
        *(short4v*)(Pw + ((po + 32) ^ swz)) = pk.s4;                          \
        pk.h2[0] = __float22bfloat162_rn(                                     \
            make_float2(EXP2F(S[12]) * a3.x, EXP2F(S[13]) * a3.y));           \
        pk.h2[1] = __float22bfloat162_rn(                                     \
            make_float2(EXP2F(S[14]) * a3.z, EXP2F(S[15]) * a3.w));           \
        *(short4v*)(Pw + ((po + 48) ^ swz)) = pk.s4;                          \
    } while (0)

    // PV A-frag early reads: rows l15 / 16+l15, keys quad*8 (+64 B for hi key
    // half). Same swizzle formula as the writes -> consistent permutation.
#define PREADS(A0, A1, B0, B1)                                                \
    do {                                                                      \
        const unsigned q16 = (unsigned)(quad * 16);                           \
        A0 = *(const bf16x8*)(Pw + (((unsigned)(l15 * 128) + q16) ^ pswz));   \
        A1 = *(const bf16x8*)(Pw + (((unsigned)((16 + l15) * 128) + q16) ^ pswz)); \
        B0 = *(const bf16x8*)(Pw + (((unsigned)(l15 * 128 + 64) + q16) ^ pswz));   \
        B1 = *(const bf16x8*)(Pw + (((unsigned)((16 + l15) * 128 + 64) + q16) ^ pswz)); \
    } while (0)

    bf16x8 ApA0, ApA1, ApB0, ApB1;       // P(it-1) fragments (reg-carried)

    // ---- prologue: stage adj(0), prefetch adj(1), K(0), V(0) ----
    float4 p0a = *(const float4*)&aptr[0];
    float4 p0b = *(const float4*)&aptr[4];            // adj(0)
    float4 ara = *(const float4*)&aptr[64];
    float4 arb = *(const float4*)&aptr[68];           // adj(1)
    bf16x8 AkA = *(const bf16x8*)&kp[0];              // K(0) lo
    bf16x8 AkB = *(const bf16x8*)&kp[32 * HDC];       // K(0) hi
    bf16x8 BvpA = *(const bf16x8*)&vp[quad * 8];      // V(0) lo
    bf16x8 BvpB = *(const bf16x8*)&vp[32 + quad * 8]; // V(0) hi

    *(float4*)((char*)&As[0][0] + ((wo)      ^ awz)) = p0a;
    *(float4*)((char*)&As[0][0] + ((wo + 16) ^ awz)) = p0b;
    LDS_BARRIER();                                    // adj(0) visible

    // ---- iter 0 (group 0): QK + exp only, PV lags one group ----
    {
        float4 arna = *(const float4*)&aptr[128];     // adj(2)
        float4 arnb = *(const float4*)&aptr[132];
        bf16x8 AkAn = *(const bf16x8*)&kp[64 * HDC];  // K(1)
        bf16x8 AkBn = *(const bf16x8*)&kp[96 * HDC];

        f32x16 S0 = __builtin_amdgcn_mfma_f32_32x32x16_bf16(AkA, Bq, Z16, 0, 0, 0);
        EXPTILE(S0, &As[0][0], 0);
        f32x16 S1 = __builtin_amdgcn_mfma_f32_32x32x16_bf16(AkB, Bq, Z16, 0, 0, 0);
        EXPTILE(S1, &As[0][0], 32);

        PREADS(ApA0, ApA1, ApB0, ApB1);               // P(0) -> regs (in-order)

        *(float4*)((char*)&As[1][0] + ((wo)      ^ awz)) = ara;   // adj(1) late
        *(float4*)((char*)&As[1][0] + ((wo + 16) ^ awz)) = arb;
        LDS_BARRIER();                                // adj(1) visible

        ara = arna; arb = arnb; AkA = AkAn; AkB = AkBn;
    }

    for (int it = 1; it < 16; ++it) {
        const int jt  = it * 64;
        const int cur = it & 1;                       // As[cur] holds adj(it)

        // next-data issues (all consumed >= 1 iteration later)
        bf16x8 BvA = *(const bf16x8*)&vp[jt + quad * 8];         // V(it)
        bf16x8 BvB = *(const bf16x8*)&vp[jt + 32 + quad * 8];
        const int nj2 = (jt + 128) & (NC - 1);
        float4 arna = *(const float4*)&aptr[nj2];                // adj(it+2)
        float4 arnb = *(const float4*)&aptr[nj2 + 4];
        bf16x8 AkAn = *(const bf16x8*)&kp[((jt + 64) & (NC - 1)) * HDC];
        bf16x8 AkBn = *(const bf16x8*)&kp[((jt + 96) & (NC - 1)) * HDC];

        f32x16 S0 = __builtin_amdgcn_mfma_f32_32x32x16_bf16(AkA, Bq, Z16, 0, 0, 0);

        __builtin_amdgcn_s_setprio(1);                // PV of group it-1 (regs)
        Cc[0] = __builtin_amdgcn_mfma_f32_16x16x32_bf16(ApA0, BvpA, Cc[0], 0, 0, 0);
        Cw[0] = __builtin_amdgcn_mfma_f32_16x16x32_bf16(ApA0, ones.v, Cw[0], 0, 0, 0);
        Cc[1] = __builtin_amdgcn_mfma_f32_16x16x32_bf16(ApA1, BvpA, Cc[1], 0, 0, 0);
        Cw[1] = __builtin_amdgcn_mfma_f32_16x16x32_bf16(ApA1, ones.v, Cw[1], 0, 0, 0);
        Cc[0] = __builtin_amdgcn_mfma_f32_16x16x32_bf16(ApB0, BvpB, Cc[0], 0, 0, 0);
        Cw[0] = __builtin_amdgcn_mfma_f32_16x16x32_bf16(ApB0, ones.v, Cw[0], 0, 0, 0);
        Cc[1] = __builtin_amdgcn_mfma_f32_16x16x32_bf16(ApB1, BvpB, Cc[1], 0, 0, 0);
        Cw[1] = __builtin_amdgcn_mfma_f32_16x16x32_bf16(ApB1, ones.v, Cw[1], 0, 0, 0);
        __builtin_amdgcn_s_setprio(0);

        EXPTILE(S0, &As[cur][0], 0);                  // writes Pw lo (reads done)
        f32x16 S1 = __builtin_amdgcn_mfma_f32_32x32x16_bf16(AkB, Bq, Z16, 0, 0, 0);
        EXPTILE(S1, &As[cur][0], 32);                 // writes Pw hi

        PREADS(ApA0, ApA1, ApB0, ApB1);               // P(it) -> regs

        *(float4*)((char*)&As[cur ^ 1][0] + ((wo)      ^ awz)) = ara;  // adj(it+1)
        *(float4*)((char*)&As[cur ^ 1][0] + ((wo + 16) ^ awz)) = arb;
        LDS_BARRIER();                                // adj(it+1) visible

        ara = arna; arb = arnb; AkA = AkAn; AkB = AkBn;
        BvpA = BvA; BvpB = BvB;
    }

    // ---- epilogue: PV of group 15 (P in regs, V(15) in Bvp) ----
    {
        Cc[0] = __builtin_amdgcn_mfma_f32_16x16x32_bf16(ApA0, BvpA, Cc[0], 0, 0, 0);
        Cw[0] = __builtin_amdgcn_mfma_f32_16x16x32_bf16(ApA0, ones.v, Cw[0], 0, 0, 0);
        Cc[1] = __builtin_amdgcn_mfma_f32_16x16x32_bf16(ApA1, BvpA, Cc[1], 0, 0, 0);
        Cw[1] = __builtin_amdgcn_mfma_f32_16x16x32_bf16(ApA1, ones.v, Cw[1], 0, 0, 0);
        Cc[0] = __builtin_amdgcn_mfma_f32_16x16x32_bf16(ApB0, BvpB, Cc[0], 0, 0, 0);
        Cw[0] = __builtin_amdgcn_mfma_f32_16x16x32_bf16(ApB0, ones.v, Cw[0], 0, 0, 0);
        Cc[1] = __builtin_amdgcn_mfma_f32_16x16x32_bf16(ApB1, BvpB, Cc[1], 0, 0, 0);
        Cw[1] = __builtin_amdgcn_mfma_f32_16x16x32_bf16(ApB1, ones.v, Cw[1], 0, 0, 0);
    }

    // epilogue: ctx[q][d] = Cc/Cw, rows q = s*16+quad*4+r, col d = l15
#pragma unroll
    for (int s = 0; s < 2; ++s)
#pragma unroll
        for (int r = 0; r < 4; ++r) {
            float den = Cw[s][r];
            float rcp = den > 0.f ? 1.f / den : 0.f;
            int row = qt0 + s * 16 + quad * 4 + r;
            cb[xb + (size_t)row * DC + h * HDC + l15] = f2bf(Cc[s][r] * rcp);
        }
#undef EXPTILE
#undef PREADS
}

extern "C" void kernel_launch(void* const* d_in, const int* in_sizes, int n_in,
                              void* d_out, int out_size, void* d_ws, size_t ws_size,
                              hipStream_t stream)
{
    const float* x   = (const float*)d_in[0];
    const float* adj = (const float*)d_in[1];
    const float* Wq  = (const float*)d_in[2];
    const float* bq  = (const float*)d_in[3];
    const float* Wk  = (const float*)d_in[4];
    const float* bk  = (const float*)d_in[5];
    const float* Wv  = (const float*)d_in[6];
    const float* bv  = (const float*)d_in[7];
    const float* Wo  = (const float*)d_in[8];
    const float* bo  = (const float*)d_in[9];
    float* out = (float*)d_out;

    const size_t tok = (size_t)BTC * NC * DC;   // 2,097,152
    short* xbf  = (short*)d_ws;
    short* Wbf  = xbf  + tok;        // 4 * 16384
    short* qbuf = Wbf  + 65536;      // head-packed [bt][h][n][16]
    short* kbuf = qbuf + tok;        // head-packed [bt][h][n][16]
    short* vt   = kbuf + tok;        // transposed  [bt][d][n]
    short* cbuf = vt   + tok;

    prep_kernel<<<2112, 256, 0, stream>>>(x, Wq, Wk, Wv, Wo, xbf, Wbf);

    dim3 pgrid(256, 3);
    proj_qkv<<<pgrid, 256, 0, stream>>>(xbf, Wbf, bq, bk, bv, qbuf, kbuf, vt);

    dim3 agrid(32, 16, 2);
    attn_kernel<<<agrid, 256, 0, stream>>>(qbuf, kbuf, vt, adj, cbuf);

    proj_out<<<256, 256, 0, stream>>>(cbuf, Wbf + 3 * 16384, bo, out);
}